// Round 6
// baseline (181.920 us; speedup 1.0000x reference)
//
#include <hip/hip_runtime.h>

// Problem constants (fixed by setup_inputs): B=4, N=4096, K=512.
#define BB 4
#define NN 4096
#define KK 512
#define QQ (KK / 4)                  // 128 k-quads; thread owns quad q = tid&127
#define BLOCK 256
#define ROWS 16                      // rows per block -> (BB*NN)/ROWS = 1024 blocks
#define GRID ((BB * NN) / ROWS)      // 1024 = 4 blocks/CU (fully co-resident)

static constexpr float W_P  = 1.0f;
static constexpr float W_C  = 1.0f;
static constexpr float EPSV = 1e-6f;

typedef float f4 __attribute__((ext_vector_type(4)));

// Symmetric 3x3 inverse of (S + eps*I), S row-major 9 floats (S is exactly
// symmetric by construction: 0.1*L*L^T + 0.1*I). Matches reference adjugate/det.
__device__ __forceinline__ void inv3_sym(const float* __restrict__ S,
                                         float& i00, float& i01, float& i02,
                                         float& i11, float& i12, float& i22) {
    float a00 = S[0] + EPSV, a01 = S[1], a02 = S[2];
    float a11 = S[4] + EPSV, a12 = S[5];
    float a22 = S[8] + EPSV;
    float c00 = a11 * a22 - a12 * a12;
    float c01 = a02 * a12 - a01 * a22;
    float c02 = a01 * a12 - a02 * a11;
    float c11 = a00 * a22 - a02 * a02;
    float c12 = a01 * a02 - a00 * a12;
    float c22 = a00 * a11 - a01 * a01;
    float det = a00 * c00 + a01 * c01 + a02 * c02;
    float r = 1.0f / det;
    i00 = c00 * r; i01 = c01 * r; i02 = c02 * r;
    i11 = c11 * r; i12 = c12 * r; i22 = c22 * r;
}

// R5 post-mortem: kernel was latency-bound (VALUBusy 11%, 930 GB/s, VGPR=64 ->
// ~1 outstanding 256B load/wave vs 900cyc HBM latency), plus 26.7 MB of HBM
// writes = L2 evicting the harness's dirty 0xAA d_ws poison on every A-miss.
// This version: (a) each thread owns k-quad q; its 4 parents' inverses are
// hoisted from LDS into 36 registers ONCE -> inner loop has no parent LDS
// traffic; (b) A is read as 8 independent nontemporal float4 loads/thread
// (1 KB/wave each, no L2 allocation -> no poison writeback); (c) global mask
// sum moved after the main loop. Epilogue: 3 relaxed device-scope fp32
// atomicAdds into d_out (no fences -- R4 lesson: agent-scope release/acquire
// lowers to L2 writeback/invalidate).
__global__ __launch_bounds__(BLOCK, 4) void main_kernel(
        const float* __restrict__ mu_c, const float* __restrict__ Sg_c,
        const float* __restrict__ mu_p, const float* __restrict__ Sg_p,
        const float* __restrict__ A,    const float* __restrict__ mask,
        float* __restrict__ out) {
    // Parent tables transposed [j][q] (parent p = 4q+j) so a thread's 4
    // fragment reads are lane-stride-16B ds_read_b128 -> conflict-free.
    __shared__ float4 sP0[4][QQ];   // mu0, mu1, mu2, i00
    __shared__ float4 sP1[4][QQ];   // 2*i01, 2*i02, i11, 2*i12
    __shared__ float  sP2[4][QQ];   // i22
    __shared__ float4 sC0[ROWS];
    __shared__ float4 sC1[ROWS];
    __shared__ float  sC2[ROWS];
    __shared__ float  sM[ROWS];
    __shared__ float  red[12];

    const int tid = threadIdx.x;
    const int rowStart = blockIdx.x * ROWS;   // global row index b*N+n
    const int b = rowStart / NN;

    // Parent staging + inversion (512 parents / 256 threads = 2 each).
    for (int p = tid; p < KK; p += BLOCK) {
        const int gp = b * KK + p;
        float i00, i01, i02, i11, i12, i22;
        inv3_sym(Sg_p + (size_t)gp * 9, i00, i01, i02, i11, i12, i22);
        const float* mu = mu_p + (size_t)gp * 3;
        sP0[p & 3][p >> 2] = make_float4(mu[0], mu[1], mu[2], i00);
        sP1[p & 3][p >> 2] = make_float4(2.0f * i01, 2.0f * i02, i11, 2.0f * i12);
        sP2[p & 3][p >> 2] = i22;
    }
    // Child staging + inversion + mask (first 16 threads).
    if (tid < ROWS) {
        const int r = rowStart + tid;
        float i00, i01, i02, i11, i12, i22;
        inv3_sym(Sg_c + (size_t)r * 9, i00, i01, i02, i11, i12, i22);
        const float* mu = mu_c + (size_t)r * 3;
        sC0[tid] = make_float4(mu[0], mu[1], mu[2], i00);
        sC1[tid] = make_float4(2.0f * i01, 2.0f * i02, i11, 2.0f * i12);
        sC2[tid] = i22;
        sM[tid] = mask[r];
    }
    __syncthreads();

    const int q = tid & (QQ - 1);   // k-quad owned by this thread
    const int h = tid >> 7;         // row half (wave-uniform)

    // Hoist this thread's 4 parents into registers (36 VGPRs); the main loop
    // never touches parent LDS again.
    float4 p0[4], p1[4];
    float  p2[4];
    #pragma unroll
    for (int s = 0; s < 4; ++s) {
        p0[s] = sP0[s][q];
        p1[s] = sP1[s][q];
        p2[s] = sP2[s][q];
    }

    const f4* __restrict__ A4 = (const f4*)A;
    float sp = 0.0f, sc = 0.0f;

    #pragma unroll
    for (int rg = 0; rg < ROWS; rg += 4) {
        const int r0 = rg + 2 * h;          // this half's first row in group
        const int r1 = r0 + 1;
        const float4 cA0 = sC0[r0], cB0 = sC1[r0];
        const float  cC0 = sC2[r0], m0  = sM[r0];
        const float4 cA1 = sC0[r1], cB1 = sC1[r1];
        const float  cC1 = sC2[r1], m1  = sM[r1];
        // Two independent nontemporal 16B loads (no L2 allocate).
        f4 a0 = __builtin_nontemporal_load(A4 + (size_t)(rowStart + r0) * QQ + q);
        f4 a1 = __builtin_nontemporal_load(A4 + (size_t)(rowStart + r1) * QQ + q);
        a0 *= m0;
        a1 *= m1;
        #pragma unroll
        for (int s = 0; s < 4; ++s) {
            {   // row r0, k = 4q+s
                float d0 = cA0.x - p0[s].x, d1 = cA0.y - p0[s].y, d2 = cA0.z - p0[s].z;
                float e00 = d0 * d0, e11 = d1 * d1, e22 = d2 * d2;
                float e01 = d0 * d1, e02 = d0 * d2, e12 = d1 * d2;
                float qp = p0[s].w * e00 + p1[s].z * e11 + p2[s] * e22
                         + p1[s].x * e01 + p1[s].y * e02 + p1[s].w * e12;
                float qc = cA0.w * e00 + cB0.z * e11 + cC0 * e22
                         + cB0.x * e01 + cB0.y * e02 + cB0.w * e12;
                sp += qp * a0[s];
                sc += qc * a0[s];
            }
            {   // row r1, k = 4q+s
                float d0 = cA1.x - p0[s].x, d1 = cA1.y - p0[s].y, d2 = cA1.z - p0[s].z;
                float e00 = d0 * d0, e11 = d1 * d1, e22 = d2 * d2;
                float e01 = d0 * d1, e02 = d0 * d2, e12 = d1 * d2;
                float qp = p0[s].w * e00 + p1[s].z * e11 + p2[s] * e22
                         + p1[s].x * e01 + p1[s].y * e02 + p1[s].w * e12;
                float qc = cA1.w * e00 + cB1.z * e11 + cC1 * e22
                         + cB1.x * e01 + cB1.y * e02 + cB1.w * e12;
                sp += qp * a1[s];
                sc += qc * a1[s];
            }
        }
    }

    // Global mask sum (after the A stream so it doesn't delay it). Same
    // deterministic order in every block -> identical denom everywhere.
    float msum = 0.0f;
    {
        const float4* m4 = (const float4*)mask;
        for (int i = tid; i < (BB * NN) / 4; i += BLOCK) {
            float4 v = m4[i];
            msum += v.x + v.y + v.z + v.w;
        }
    }

    // Block reduction of sp, sc, msum: wave-64 shuffle then cross-wave LDS.
    #pragma unroll
    for (int off = 32; off > 0; off >>= 1) {
        sp   += __shfl_down(sp, off);
        sc   += __shfl_down(sc, off);
        msum += __shfl_down(msum, off);
    }
    const int wave = tid >> 6;
    if ((tid & 63) == 0) {
        red[wave * 3]     = sp;
        red[wave * 3 + 1] = sc;
        red[wave * 3 + 2] = msum;
    }
    __syncthreads();
    if (tid == 0) {
        float tp = red[0] + red[3] + red[6] + red[9];
        float tc = red[1] + red[4] + red[7] + red[10];
        float tm = red[2] + red[5] + red[8] + red[11];
        float denom = fmaxf(tm, 1.0f);           // identical in every block
        // Relaxed device-scope fp32 atomics: no fence, no L2 writeback.
        atomicAdd(out + 0, (W_P * tp + W_C * tc) / denom);
        atomicAdd(out + 1, tp / denom);
        atomicAdd(out + 2, tc / denom);
    }
}

extern "C" void kernel_launch(void* const* d_in, const int* in_sizes, int n_in,
                              void* d_out, int out_size, void* d_ws, size_t ws_size,
                              hipStream_t stream) {
    const float* mu_c = (const float*)d_in[0];
    const float* Sg_c = (const float*)d_in[1];
    const float* mu_p = (const float*)d_in[2];
    const float* Sg_p = (const float*)d_in[3];
    const float* A    = (const float*)d_in[4];
    const float* mask = (const float*)d_in[5];
    float* out = (float*)d_out;

    main_kernel<<<GRID, BLOCK, 0, stream>>>(mu_c, Sg_c, mu_p, Sg_p, A, mask, out);
}

// Round 7
// 125.698 us; speedup vs baseline: 1.4473x; 1.4473x over previous
//
#include <hip/hip_runtime.h>

// Problem constants (fixed by setup_inputs): B=4, N=4096, K=512.
#define BB 4
#define NN 4096
#define KK 512
#define QQ (KK / 4)                  // 128 k-quads; thread owns quad q = tid&127
#define BLOCK 256
#define ROWS 16                      // rows per block -> (BB*NN)/ROWS = 1024 blocks
#define GRID ((BB * NN) / ROWS)      // 1024 blocks

static constexpr float W_P  = 1.0f;
static constexpr float W_C  = 1.0f;
static constexpr float EPSV = 1e-6f;

typedef float f4 __attribute__((ext_vector_type(4)));

// Symmetric 3x3 inverse of (S + eps*I), S row-major 9 floats (S is exactly
// symmetric by construction: 0.1*L*L^T + 0.1*I). Matches reference adjugate/det.
__device__ __forceinline__ void inv3_sym(const float* __restrict__ S,
                                         float& i00, float& i01, float& i02,
                                         float& i11, float& i12, float& i22) {
    float a00 = S[0] + EPSV, a01 = S[1], a02 = S[2];
    float a11 = S[4] + EPSV, a12 = S[5];
    float a22 = S[8] + EPSV;
    float c00 = a11 * a22 - a12 * a12;
    float c01 = a02 * a12 - a01 * a22;
    float c02 = a01 * a12 - a02 * a11;
    float c11 = a00 * a22 - a02 * a02;
    float c12 = a01 * a02 - a00 * a12;
    float c22 = a00 * a11 - a01 * a01;
    float det = a00 * c00 + a01 * c01 + a02 * c02;
    float r = 1.0f / det;
    i00 = c00 * r; i01 = c01 * r; i02 = c02 * r;
    i11 = c11 * r; i12 = c12 * r; i22 = c22 * r;
}

// R6 post-mortem: nontemporal A-loads quadrupled FETCH (123 MB) and exploded
// WRITE (196 MB) -> never bypass L2/L3 on streaming reads here. This version:
//  - regular cached float4 A loads, thread owns k-quad q; all 8 loads issued
//    BEFORE LDS staging so HBM latency (~900cyc) overlaps parent inversion.
//  - mask-sum first (R5 measured it ~free when L2-warm ordering is preserved).
//  - parent fragments hoisted LDS->36 regs once; compute loop touches no LDS
//    except wave-uniform child broadcasts.
//  - epilogue: 3 relaxed device-scope fp32 atomicAdds into d_out. NO fences
//    (R4: agent-scope release/acquire => L2 writeback/invalidate, +12us), no
//    cooperative launch (R3: silently fails under graph capture).
__global__ __launch_bounds__(BLOCK) void main_kernel(
        const float* __restrict__ mu_c, const float* __restrict__ Sg_c,
        const float* __restrict__ mu_p, const float* __restrict__ Sg_p,
        const float* __restrict__ A,    const float* __restrict__ mask,
        float* __restrict__ out) {
    // Parent tables transposed [j][q] (parent p = 4q+j): a thread's 4 fragment
    // reads are contiguous-16B-per-lane ds_read_b128, standard pattern.
    __shared__ float4 sP0[4][QQ];   // mu0, mu1, mu2, i00
    __shared__ float4 sP1[4][QQ];   // 2*i01, 2*i02, i11, 2*i12
    __shared__ float  sP2[4][QQ];   // i22
    __shared__ float4 sC0[ROWS];
    __shared__ float4 sC1[ROWS];
    __shared__ float  sC2[ROWS];
    __shared__ float  sM[ROWS];
    __shared__ float  red[12];

    const int tid = threadIdx.x;
    const int rowStart = blockIdx.x * ROWS;   // global row index b*N+n
    const int b = rowStart / NN;
    const int q = tid & (QQ - 1);             // owned k-quad
    const int h = tid >> 7;                   // row half (wave-uniform)

    // ---- Issue all 8 A tile loads first (maximum MLP; consumed last). ----
    const f4* __restrict__ A4 = (const f4*)A;
    f4 a[8];
    #pragma unroll
    for (int g = 0; g < 4; ++g) {
        const size_t r0 = (size_t)(rowStart + 4 * g + 2 * h) * QQ + q;
        a[2 * g]     = A4[r0];
        a[2 * g + 1] = A4[r0 + QQ];
    }

    // ---- Global mask sum (identical deterministic order in every block). ----
    float msum = 0.0f;
    {
        const float4* m4 = (const float4*)mask;
        #pragma unroll
        for (int i = tid; i < (BB * NN) / 4; i += BLOCK) {
            float4 v = m4[i];
            msum += v.x + v.y + v.z + v.w;
        }
    }

    // ---- Parent staging + inversion (512 parents / 256 threads = 2 each). ----
    for (int p = tid; p < KK; p += BLOCK) {
        const int gp = b * KK + p;
        float i00, i01, i02, i11, i12, i22;
        inv3_sym(Sg_p + (size_t)gp * 9, i00, i01, i02, i11, i12, i22);
        const float* mu = mu_p + (size_t)gp * 3;
        sP0[p & 3][p >> 2] = make_float4(mu[0], mu[1], mu[2], i00);
        sP1[p & 3][p >> 2] = make_float4(2.0f * i01, 2.0f * i02, i11, 2.0f * i12);
        sP2[p & 3][p >> 2] = i22;
    }
    // Child staging + inversion + mask (first 16 threads).
    if (tid < ROWS) {
        const int r = rowStart + tid;
        float i00, i01, i02, i11, i12, i22;
        inv3_sym(Sg_c + (size_t)r * 9, i00, i01, i02, i11, i12, i22);
        const float* mu = mu_c + (size_t)r * 3;
        sC0[tid] = make_float4(mu[0], mu[1], mu[2], i00);
        sC1[tid] = make_float4(2.0f * i01, 2.0f * i02, i11, 2.0f * i12);
        sC2[tid] = i22;
        sM[tid] = mask[r];
    }
    __syncthreads();

    // ---- Hoist this thread's 4 parents into registers (one-time LDS read). --
    float4 p0[4], p1[4];
    float  p2[4];
    #pragma unroll
    for (int s = 0; s < 4; ++s) {
        p0[s] = sP0[s][q];
        p1[s] = sP1[s][q];
        p2[s] = sP2[s][q];
    }

    float sp = 0.0f, sc = 0.0f;

    #pragma unroll
    for (int g = 0; g < 4; ++g) {
        const int r0 = 4 * g + 2 * h;       // this half's rows in group g
        const int r1 = r0 + 1;
        const float4 cA0 = sC0[r0], cB0 = sC1[r0];
        const float  cC0 = sC2[r0], m0  = sM[r0];
        const float4 cA1 = sC0[r1], cB1 = sC1[r1];
        const float  cC1 = sC2[r1], m1  = sM[r1];
        f4 a0 = a[2 * g]     * m0;
        f4 a1 = a[2 * g + 1] * m1;
        #pragma unroll
        for (int s = 0; s < 4; ++s) {
            {   // row r0, k = 4q+s
                float d0 = cA0.x - p0[s].x, d1 = cA0.y - p0[s].y, d2 = cA0.z - p0[s].z;
                float e00 = d0 * d0, e11 = d1 * d1, e22 = d2 * d2;
                float e01 = d0 * d1, e02 = d0 * d2, e12 = d1 * d2;
                float qp = p0[s].w * e00 + p1[s].z * e11 + p2[s] * e22
                         + p1[s].x * e01 + p1[s].y * e02 + p1[s].w * e12;
                float qc = cA0.w * e00 + cB0.z * e11 + cC0 * e22
                         + cB0.x * e01 + cB0.y * e02 + cB0.w * e12;
                sp += qp * a0[s];
                sc += qc * a0[s];
            }
            {   // row r1, k = 4q+s
                float d0 = cA1.x - p0[s].x, d1 = cA1.y - p0[s].y, d2 = cA1.z - p0[s].z;
                float e00 = d0 * d0, e11 = d1 * d1, e22 = d2 * d2;
                float e01 = d0 * d1, e02 = d0 * d2, e12 = d1 * d2;
                float qp = p0[s].w * e00 + p1[s].z * e11 + p2[s] * e22
                         + p1[s].x * e01 + p1[s].y * e02 + p1[s].w * e12;
                float qc = cA1.w * e00 + cB1.z * e11 + cC1 * e22
                         + cB1.x * e01 + cB1.y * e02 + cB1.w * e12;
                sp += qp * a1[s];
                sc += qc * a1[s];
            }
        }
    }

    // ---- Block reduction: wave-64 shuffle then cross-wave LDS. ----
    #pragma unroll
    for (int off = 32; off > 0; off >>= 1) {
        sp   += __shfl_down(sp, off);
        sc   += __shfl_down(sc, off);
        msum += __shfl_down(msum, off);
    }
    const int wave = tid >> 6;
    if ((tid & 63) == 0) {
        red[wave * 3]     = sp;
        red[wave * 3 + 1] = sc;
        red[wave * 3 + 2] = msum;
    }
    __syncthreads();
    if (tid == 0) {
        float tp = red[0] + red[3] + red[6] + red[9];
        float tc = red[1] + red[4] + red[7] + red[10];
        float tm = red[2] + red[5] + red[8] + red[11];
        float denom = fmaxf(tm, 1.0f);           // identical in every block
        // Relaxed device-scope fp32 atomics: no fence, no L2 writeback.
        atomicAdd(out + 0, (W_P * tp + W_C * tc) / denom);
        atomicAdd(out + 1, tp / denom);
        atomicAdd(out + 2, tc / denom);
    }
}

extern "C" void kernel_launch(void* const* d_in, const int* in_sizes, int n_in,
                              void* d_out, int out_size, void* d_ws, size_t ws_size,
                              hipStream_t stream) {
    const float* mu_c = (const float*)d_in[0];
    const float* Sg_c = (const float*)d_in[1];
    const float* mu_p = (const float*)d_in[2];
    const float* Sg_p = (const float*)d_in[3];
    const float* A    = (const float*)d_in[4];
    const float* mask = (const float*)d_in[5];
    float* out = (float*)d_out;

    main_kernel<<<GRID, BLOCK, 0, stream>>>(mu_c, Sg_c, mu_p, Sg_p, A, mask, out);
}